// Round 10
// baseline (772.182 us; speedup 1.0000x reference)
//
#include <hip/hip_runtime.h>

typedef __bf16 bf16x8 __attribute__((ext_vector_type(8)));
typedef float  f32x4  __attribute__((ext_vector_type(4)));

#define LDA 136       // padded bf16 row stride for GEMM LDS tiles
#define NB_MAX 1024   // max 128-node buckets (N<=131072)

static __device__ __forceinline__ unsigned short f2bf(float f) {
  unsigned int u = __float_as_uint(f);
  u += 0x7fffu + ((u >> 16) & 1u);
  return (unsigned short)(u >> 16);
}
static __device__ __forceinline__ float bflo(unsigned int u) {
  return __uint_as_float(u << 16);
}
static __device__ __forceinline__ float bfhi(unsigned int u) {
  return __uint_as_float(u & 0xFFFF0000u);
}
static __device__ __forceinline__ unsigned int packbf2(float a, float b) {
  return (unsigned int)f2bf(a) | ((unsigned int)f2bf(b) << 16);
}

// ---------- prep: zero counters/stats + convert weights to bf16 (one dispatch)
__global__ void prep(const float* __restrict__ W1, const float* __restrict__ W2,
                     const float* __restrict__ W3, unsigned short* __restrict__ w1b,
                     unsigned short* __restrict__ w2b, unsigned short* __restrict__ w3b,
                     int* __restrict__ bcnt, float* __restrict__ s1,
                     float* __restrict__ s2, int nb) {
  int i = blockIdx.x * blockDim.x + threadIdx.x;
  if (i < nb) bcnt[i] = 0;
  if (i < 256) { s1[i] = 0.f; s2[i] = 0.f; }
  if (i < 16384) {
    w1b[i] = f2bf(W1[i]);
    w2b[i] = f2bf(W2[i]);
  } else if (i < 18432) {
    int j = i - 16384;  // 16x128 padded W3
    w3b[j] = (j < 1280) ? f2bf(W3[j]) : 0;
  }
}

// ---------- fp32 -> bf16 cast ----------
__global__ void cvt_bf16(const float* __restrict__ x,
                         unsigned short* __restrict__ o, long long n) {
  long long i = ((long long)blockIdx.x * blockDim.x + threadIdx.x) * 4;
  if (i < n) {
    float4 v = *(const float4*)(x + i);
    uint2 w;
    w.x = packbf2(v.x, v.y);
    w.y = packbf2(v.z, v.w);
    *(uint2*)(o + i) = w;
  }
}

// ---------- bucket histogram (bucket = dst >> 7); saves per-block hists ------
__global__ void bucket_hist(const int* __restrict__ ei, int* __restrict__ bcnt,
                            int* __restrict__ bhist, int E, int NB) {
  __shared__ int h[NB_MAX];
  for (int i = threadIdx.x; i < NB; i += blockDim.x) h[i] = 0;
  __syncthreads();
  int chunk = (E + gridDim.x - 1) / gridDim.x;
  int e0 = blockIdx.x * chunk;
  int e1 = min(e0 + chunk, E);
  for (int e = e0 + (int)threadIdx.x; e < e1; e += blockDim.x)
    atomicAdd(&h[ei[E + e] >> 7], 1);
  __syncthreads();
  for (int i = threadIdx.x; i < NB; i += blockDim.x) {
    bhist[blockIdx.x * NB + i] = h[i];
    if (h[i]) atomicAdd(&bcnt[i], h[i]);
  }
}

// ---------- scan bucket counts (NB<=1024, single chunk) ----------
__global__ void scan_buckets(const int* __restrict__ cnt,
                             int* __restrict__ bstart, int* __restrict__ gcur,
                             int n) {
  __shared__ int tmp[1024];
  int i = threadIdx.x;
  int v = (i < n) ? cnt[i] : 0;
  tmp[i] = v;
  __syncthreads();
  for (int off = 1; off < 1024; off <<= 1) {
    int t = (i >= off) ? tmp[i - off] : 0;
    __syncthreads();
    tmp[i] += t;
    __syncthreads();
  }
  if (i == 0) bstart[0] = 0;
  if (i < n) {
    bstart[i + 1] = tmp[i];
    gcur[i] = tmp[i] - v;  // exclusive
  }
}

// ---------- partition edges using precomputed per-block hists ----------
__global__ void partition_edges(const int* __restrict__ ei,
                                int* __restrict__ gcur,
                                const int* __restrict__ bhist,
                                unsigned int* __restrict__ part, int E, int NB) {
  __shared__ int base[NB_MAX];
  __shared__ int cur[NB_MAX];
  int chunk = (E + gridDim.x - 1) / gridDim.x;
  int e0 = blockIdx.x * chunk;
  int e1 = min(e0 + chunk, E);
  for (int i = threadIdx.x; i < NB; i += blockDim.x) {
    int hv = bhist[blockIdx.x * NB + i];
    cur[i] = 0;
    base[i] = hv ? atomicAdd(&gcur[i], hv) : 0;
  }
  __syncthreads();
  for (int e = e0 + (int)threadIdx.x; e < e1; e += blockDim.x) {
    int d = ei[E + e];
    int b = d >> 7;
    int slot = base[b] + atomicAdd(&cur[b], 1);
    part[slot] = (unsigned int)ei[e] | ((unsigned int)(d & 127) << 17);
  }
}

// ---------- counting-sort each bucket -> csr + rs ----------
__global__ void __launch_bounds__(256)
csr_fill(const unsigned int* __restrict__ part, const int* __restrict__ bstart,
         int* __restrict__ rs, int* __restrict__ csr, int N, int NB) {
  __shared__ int h[128];
  __shared__ int off[128];
  const int b = blockIdx.x;
  const int e0 = bstart[b], e1 = bstart[b + 1];
  const int tid = threadIdx.x;
  if (tid < 128) h[tid] = 0;
  __syncthreads();
  for (int i = e0 + tid; i < e1; i += 256)
    atomicAdd(&h[part[i] >> 17], 1);
  __syncthreads();
  if (tid < 128) off[tid] = h[tid];
  __syncthreads();
  for (int s = 1; s < 128; s <<= 1) {
    int v = (tid < 128 && tid >= s) ? off[tid - s] : 0;
    __syncthreads();
    if (tid < 128) off[tid] += v;
    __syncthreads();
  }
  if (tid < 128) {
    int excl = e0 + off[tid] - h[tid];
    int node = b * 128 + tid;
    if (node < N) rs[node] = excl;
    h[tid] = excl;  // reuse as cursor
  }
  if (b == NB - 1 && tid == 0) rs[N] = e1;
  __syncthreads();
  for (int i = e0 + tid; i < e1; i += 256) {
    unsigned int p = part[i];
    int slot = atomicAdd(&h[p >> 17], 1);
    csr[slot] = (int)(p & 0x1FFFF);
  }
}

// ---------- sort each adjacency list by src (phase-coherent gathers) ----------
// one thread per node; LDS insertion sort; deg>96 skipped (sort is optional)
__global__ void __launch_bounds__(64)
adj_sort(const int* __restrict__ rs, int* __restrict__ csr, int N) {
  __shared__ int buf[64 * 97];  // 97 stride breaks bank correlation
  int node = blockIdx.x * 64 + (int)threadIdx.x;
  if (node >= N) return;
  int b = rs[node], e = rs[node + 1];
  int d = e - b;
  if (d > 96) return;
  int* m = buf + threadIdx.x * 97;
  for (int i = 0; i < d; ++i) m[i] = csr[b + i];
  for (int i = 1; i < d; ++i) {
    int key = m[i];
    int j = i - 1;
    while (j >= 0 && m[j] > key) { m[j + 1] = m[j]; --j; }
    m[j + 1] = key;
  }
  for (int i = 0; i < d; ++i) csr[b + i] = m[i];
}

// ---------- aggregation: agg[i] = t[i] + sum_j t[j], bf16, fp32 acc ----------
// one wave per node; 16 lanes x 16B cover a row; 4 edges per VMEM instruction
__global__ void __launch_bounds__(256)
csr_agg128(const unsigned short* __restrict__ t, const int* __restrict__ rs,
           const int* __restrict__ csr, unsigned short* __restrict__ agg,
           int N) {
  int node = blockIdx.x * 4 + (threadIdx.x >> 6);
  if (node >= N) return;
  const int lane = threadIdx.x & 63;
  const int q = lane >> 4;   // quarter 0..3 -> edge stride phase
  const int ql = lane & 15;  // lane within quarter
  const int c = ql * 8;      // bf16 column (16B per lane)
  float a0 = 0.f, a1 = 0.f, a2 = 0.f, a3 = 0.f;
  float a4 = 0.f, a5 = 0.f, a6 = 0.f, a7 = 0.f;
  const int b = rs[node], e = rs[node + 1];
  int i = b + q;
  for (; i + 4 < e; i += 8) {  // 2 independent 1KB gathers in flight
    int j0 = csr[i], j1 = csr[i + 4];
    uint4 v0 = *(const uint4*)(t + (long long)j0 * 128 + c);
    uint4 v1 = *(const uint4*)(t + (long long)j1 * 128 + c);
    a0 += bflo(v0.x) + bflo(v1.x);  a1 += bfhi(v0.x) + bfhi(v1.x);
    a2 += bflo(v0.y) + bflo(v1.y);  a3 += bfhi(v0.y) + bfhi(v1.y);
    a4 += bflo(v0.z) + bflo(v1.z);  a5 += bfhi(v0.z) + bfhi(v1.z);
    a6 += bflo(v0.w) + bflo(v1.w);  a7 += bfhi(v0.w) + bfhi(v1.w);
  }
  if (i < e) {
    int j = csr[i];
    uint4 v = *(const uint4*)(t + (long long)j * 128 + c);
    a0 += bflo(v.x);  a1 += bfhi(v.x);
    a2 += bflo(v.y);  a3 += bfhi(v.y);
    a4 += bflo(v.z);  a5 += bfhi(v.z);
    a6 += bflo(v.w);  a7 += bfhi(v.w);
  }
  // reduce across the 4 quarters (lanes ^16, ^32)
  a0 += __shfl_xor(a0, 16, 64);  a1 += __shfl_xor(a1, 16, 64);
  a2 += __shfl_xor(a2, 16, 64);  a3 += __shfl_xor(a3, 16, 64);
  a4 += __shfl_xor(a4, 16, 64);  a5 += __shfl_xor(a5, 16, 64);
  a6 += __shfl_xor(a6, 16, 64);  a7 += __shfl_xor(a7, 16, 64);
  a0 += __shfl_xor(a0, 32, 64);  a1 += __shfl_xor(a1, 32, 64);
  a2 += __shfl_xor(a2, 32, 64);  a3 += __shfl_xor(a3, 32, 64);
  a4 += __shfl_xor(a4, 32, 64);  a5 += __shfl_xor(a5, 32, 64);
  a6 += __shfl_xor(a6, 32, 64);  a7 += __shfl_xor(a7, 32, 64);
  if (q == 0) {
    uint4 sv = *(const uint4*)(t + (long long)node * 128 + c);  // self term
    uint4 w;
    w.x = packbf2(a0 + bflo(sv.x), a1 + bfhi(sv.x));
    w.y = packbf2(a2 + bflo(sv.y), a3 + bfhi(sv.y));
    w.z = packbf2(a4 + bflo(sv.z), a5 + bfhi(sv.z));
    w.w = packbf2(a6 + bflo(sv.w), a7 + bfhi(sv.w));
    *(uint4*)(agg + (long long)node * 128 + c) = w;
  }
}

// ---------- layer-3 aggregation on bf16 y[N,16] (8 lanes/node) ----------
__global__ void __launch_bounds__(256)
csr_agg10b(const unsigned short* __restrict__ y, const int* __restrict__ rs,
           const int* __restrict__ csr, const float* __restrict__ b3,
           float* __restrict__ out, int N) {
  int t = blockIdx.x * blockDim.x + threadIdx.x;
  int node = t >> 3;
  int c = (t & 7) * 2;
  if (node >= N) return;
  unsigned int sv = *(const unsigned int*)(y + node * 16 + c);
  float a0 = bflo(sv), a1 = bfhi(sv);
  int b = rs[node], e = rs[node + 1];
  int i = b;
  for (; i + 3 < e; i += 4) {
    int j0 = csr[i], j1 = csr[i + 1], j2 = csr[i + 2], j3 = csr[i + 3];
    unsigned int v0 = *(const unsigned int*)(y + j0 * 16 + c);
    unsigned int v1 = *(const unsigned int*)(y + j1 * 16 + c);
    unsigned int v2 = *(const unsigned int*)(y + j2 * 16 + c);
    unsigned int v3 = *(const unsigned int*)(y + j3 * 16 + c);
    a0 += bflo(v0) + bflo(v1) + bflo(v2) + bflo(v3);
    a1 += bfhi(v0) + bfhi(v1) + bfhi(v2) + bfhi(v3);
  }
  for (; i < e; ++i) {
    unsigned int v = *(const unsigned int*)(y + csr[i] * 16 + c);
    a0 += bflo(v);
    a1 += bfhi(v);
  }
  if (c < 10) {
    float2 o;
    o.x = a0 + b3[c];
    o.y = a1 + b3[c + 1];
    *(float2*)(out + node * 10 + c) = o;  // 40*node+8*(c/2): 8B aligned
  }
}

// ---------- fused: compute BN coeffs from stats, then o = relu(h*sc+sh) ------
__global__ void __launch_bounds__(256)
affine_bn(const unsigned short* __restrict__ h, const float* __restrict__ stats,
          const float* __restrict__ g, const float* __restrict__ be,
          unsigned short* __restrict__ o, int N, float invN) {
  __shared__ float lsc[128], lsh[128];
  const int t = threadIdx.x;
  if (t < 128) {
    float mean = stats[t] * invN;
    float var = stats[128 + t] * invN - mean * mean;
    float s = g[t] * rsqrtf(var + 1e-5f);
    lsc[t] = s;
    lsh[t] = be[t] - mean * s;
  }
  __syncthreads();
  long long tid = (long long)blockIdx.x * blockDim.x + t;
  if (tid >= (long long)N * 16) return;
  int row = (int)(tid >> 4);
  int c = (int)(tid & 15) << 3;
  uint4 w = *(const uint4*)(h + (long long)row * 128 + c);
  float r0 = fmaxf(fmaf(bflo(w.x), lsc[c + 0], lsh[c + 0]), 0.f);
  float r1 = fmaxf(fmaf(bfhi(w.x), lsc[c + 1], lsh[c + 1]), 0.f);
  float r2 = fmaxf(fmaf(bflo(w.y), lsc[c + 2], lsh[c + 2]), 0.f);
  float r3 = fmaxf(fmaf(bfhi(w.y), lsc[c + 3], lsh[c + 3]), 0.f);
  float r4 = fmaxf(fmaf(bflo(w.z), lsc[c + 4], lsh[c + 4]), 0.f);
  float r5 = fmaxf(fmaf(bfhi(w.z), lsc[c + 5], lsh[c + 5]), 0.f);
  float r6 = fmaxf(fmaf(bflo(w.w), lsc[c + 6], lsh[c + 6]), 0.f);
  float r7 = fmaxf(fmaf(bfhi(w.w), lsc[c + 7], lsh[c + 7]), 0.f);
  uint4 ow;
  ow.x = packbf2(r0, r1);
  ow.y = packbf2(r2, r3);
  ow.z = packbf2(r4, r5);
  ow.w = packbf2(r6, r7);
  *(uint4*)(o + (long long)row * 128 + c) = ow;
}

// ---------- GEMM: h_bf16 = A_bf16 @ Wb^T + bias, fused BN stats --------------
// epilogue routes C through LDS (sA reuse) for coalesced 16B stores
__global__ void __launch_bounds__(256)
gemm128(const unsigned short* __restrict__ Ab, const unsigned short* __restrict__ Wb,
        const float* __restrict__ bias, unsigned short* __restrict__ Hb,
        float* __restrict__ stats, int M) {
  __shared__ __align__(16) unsigned short sA[128 * LDA];
  __shared__ __align__(16) unsigned short sB[128 * LDA];
  __shared__ float sSum[128], sSq[128];
  const int tid = threadIdx.x;
  const int row0 = blockIdx.x * 128;

  if (tid < 128) { sSum[tid] = 0.f; sSq[tid] = 0.f; }
  for (int j = 0; j < 8; ++j) {
    int flat = j * 2048 + tid * 8;
    int r = flat >> 7, c = flat & 127;
    int gr = row0 + r;
    uint4 v = make_uint4(0, 0, 0, 0);
    if (gr < M) v = *(const uint4*)(Ab + (long long)gr * 128 + c);
    *(uint4*)(sA + r * LDA + c) = v;
  }
  for (int j = 0; j < 8; ++j) {  // W already bf16: straight copies
    int flat = j * 2048 + tid * 8;
    int r = flat >> 7, c = flat & 127;
    *(uint4*)(sB + r * LDA + c) = *(const uint4*)(Wb + flat);
  }
  __syncthreads();

  const int lane = tid & 63, wid = tid >> 6;
  const int wM = (wid >> 1) * 64, wN = (wid & 1) * 64;
  const int l15 = lane & 15, quad = lane >> 4;
  f32x4 acc[4][4] = {};

  for (int kk = 0; kk < 4; ++kk) {
    const int kb = kk * 32 + quad * 8;
    bf16x8 af[4], bfr[4];
    for (int mi = 0; mi < 4; ++mi)
      af[mi] = *reinterpret_cast<const bf16x8*>(sA + (wM + mi * 16 + l15) * LDA + kb);
    for (int ni = 0; ni < 4; ++ni)
      bfr[ni] = *reinterpret_cast<const bf16x8*>(sB + (wN + ni * 16 + l15) * LDA + kb);
    for (int mi = 0; mi < 4; ++mi)
      for (int ni = 0; ni < 4; ++ni)
        acc[mi][ni] = __builtin_amdgcn_mfma_f32_16x16x32_bf16(
            af[mi], bfr[ni], acc[mi][ni], 0, 0, 0);
  }
  __syncthreads();  // done with sA as A-tile; reuse as C staging

  // epilogue: stats (fp32, pre-rounding) + bf16 C into LDS
  for (int ni = 0; ni < 4; ++ni) {
    int col = wN + ni * 16 + l15;
    float bv = bias[col];
    float s = 0.f, q = 0.f;
    for (int mi = 0; mi < 4; ++mi) {
      int rloc = wM + mi * 16 + quad * 4;
      for (int r = 0; r < 4; ++r) {
        if (row0 + rloc + r < M) {
          float v = acc[mi][ni][r] + bv;
          sA[(rloc + r) * LDA + col] = f2bf(v);
          s += v;
          q += v * v;
        }
      }
    }
    atomicAdd(&sSum[col], s);
    atomicAdd(&sSq[col], q);
  }
  __syncthreads();
  if (tid < 128) {
    atomicAdd(&stats[tid], sSum[tid]);
    atomicAdd(&stats[128 + tid], sSq[tid]);
  }
  for (int j = 0; j < 8; ++j) {  // coalesced 16B stores
    int flat = j * 2048 + tid * 8;
    int r = flat >> 7, c = flat & 127;
    int gr = row0 + r;
    if (gr < M)
      *(uint4*)(Hb + (long long)gr * 128 + c) = *(const uint4*)(sA + r * LDA + c);
  }
}

// ---------- y_bf16[M,16] = A_bf16 @ w3b[16,128]^T, coalesced via LDS ---------
__global__ void __launch_bounds__(256)
gemm_y(const unsigned short* __restrict__ Ab, const unsigned short* __restrict__ w3b,
       unsigned short* __restrict__ Y, int M) {
  __shared__ __align__(16) unsigned short sA[128 * LDA];
  __shared__ __align__(16) unsigned short sB[16 * LDA];
  const int tid = threadIdx.x;
  const int row0 = blockIdx.x * 128;

  for (int j = 0; j < 8; ++j) {
    int flat = j * 2048 + tid * 8;
    int r = flat >> 7, c = flat & 127;
    int gr = row0 + r;
    uint4 v = make_uint4(0, 0, 0, 0);
    if (gr < M) v = *(const uint4*)(Ab + (long long)gr * 128 + c);
    *(uint4*)(sA + r * LDA + c) = v;
  }
  {
    int flat = tid * 8;  // 2048 elems = 256 threads x 8
    int r = flat >> 7, c = flat & 127;
    *(uint4*)(sB + r * LDA + c) = *(const uint4*)(w3b + flat);
  }
  __syncthreads();

  const int lane = tid & 63, wid = tid >> 6;
  const int l15 = lane & 15, quad = lane >> 4;
  f32x4 acc[2] = {};
  for (int kk = 0; kk < 4; ++kk) {
    const int kb = kk * 32 + quad * 8;
    bf16x8 b = *reinterpret_cast<const bf16x8*>(sB + l15 * LDA + kb);
    for (int mi = 0; mi < 2; ++mi) {
      bf16x8 a = *reinterpret_cast<const bf16x8*>(
          sA + (wid * 32 + mi * 16 + l15) * LDA + kb);
      acc[mi] = __builtin_amdgcn_mfma_f32_16x16x32_bf16(a, b, acc[mi], 0, 0, 0);
    }
  }
  __syncthreads();  // reuse sA as 128x16 C staging (stride 16)
  for (int mi = 0; mi < 2; ++mi)
    for (int r = 0; r < 4; ++r) {
      int rloc = wid * 32 + mi * 16 + quad * 4 + r;
      sA[rloc * 16 + l15] = (l15 < 10) ? f2bf(acc[mi][r]) : 0;
    }
  __syncthreads();
  {  // 128 rows x 16 cols = 2048 bf16 = 256 threads x 8 (one uint4 each)
    int flat = tid * 8;
    int gr = row0 + (flat >> 4);
    if (gr < M) *(uint4*)(Y + (long long)gr * 16 + (flat & 15)) =
        *(const uint4*)(sA + flat);
  }
}

// ---------- host ----------
extern "C" void kernel_launch(void* const* d_in, const int* in_sizes, int n_in,
                              void* d_out, int out_size, void* d_ws,
                              size_t ws_size, hipStream_t stream) {
  const float* x  = (const float*)d_in[0];
  const int*   ei = (const int*)d_in[1];  // int32 per harness contract
  const float* W1 = (const float*)d_in[2];
  const float* b1 = (const float*)d_in[3];
  const float* g1 = (const float*)d_in[4];
  const float* be1 = (const float*)d_in[5];
  const float* W2 = (const float*)d_in[6];
  const float* b2 = (const float*)d_in[7];
  const float* g2 = (const float*)d_in[8];
  const float* be2 = (const float*)d_in[9];
  const float* W3 = (const float*)d_in[10];
  const float* b3 = (const float*)d_in[11];

  const int N = in_sizes[0] / 128;
  const int E = in_sizes[1] / 2;
  const int NB = (N + 127) / 128;  // 128-node buckets

  // workspace layout (~92 MB); 16B-aligned arrays first
  unsigned short* featb = (unsigned short*)d_ws;              // N*128 bf16
  unsigned short* aggb  = featb + (size_t)N * 128;            // N*128 bf16
  unsigned short* hb    = aggb + (size_t)N * 128;             // N*128 bf16
  unsigned short* w1b   = hb + (size_t)N * 128;               // 16384
  unsigned short* w2b   = w1b + 16384;                        // 16384
  unsigned short* w3b   = w2b + 16384;                        // 2048
  int*   csr = (int*)(w3b + 2048);                            // E ints
  int*   rs  = csr + E;                                       // N+1
  int* bcnt  = rs + N + 1;                                    // NB
  int* bstart = bcnt + NB;                                    // NB+1
  int* gcur  = bstart + NB + 1;                               // NB
  int* bhist = gcur + NB;                                     // 256*NB
  float* stats1 = (float*)(bhist + 256 * NB);                 // 256
  float* stats2 = stats1 + 256;                               // 256
  unsigned int* part = (unsigned int*)hb;  // aliases hb (dead until layer-1 gemm)
  unsigned short* y = aggb;                // aliases aggb (free in layer 3)
  float* out = (float*)d_out;

  const int TPB = 256;
  const int cvtBlocks   = (int)(((long long)N * 32 + TPB - 1) / TPB);
  const int affBlocks   = (int)(((long long)N * 16 + TPB - 1) / TPB);
  const int aggBlocks   = (N + 3) / 4;
  const int agg10Blocks = (N * 8 + TPB - 1) / TPB;
  const int gemmBlocks  = (N + 127) / 128;
  const int sortBlocks  = (N + 63) / 64;
  const float invN = 1.0f / (float)N;

  // ---- build: weights + CSR (sorted adjacency) ----
  prep<<<72, TPB, 0, stream>>>(W1, W2, W3, w1b, w2b, w3b, bcnt, stats1, stats2, NB);
  bucket_hist<<<256, TPB, 0, stream>>>(ei, bcnt, bhist, E, NB);
  scan_buckets<<<1, 1024, 0, stream>>>(bcnt, bstart, gcur, NB);
  partition_edges<<<256, TPB, 0, stream>>>(ei, gcur, bhist, part, E, NB);
  csr_fill<<<NB, TPB, 0, stream>>>(part, bstart, rs, csr, N, NB);
  adj_sort<<<sortBlocks, 64, 0, stream>>>(rs, csr, N);

  // ---- layer 1 ----
  cvt_bf16<<<cvtBlocks, TPB, 0, stream>>>(x, featb, (long long)N * 128);
  csr_agg128<<<aggBlocks, TPB, 0, stream>>>(featb, rs, csr, aggb, N);
  gemm128<<<gemmBlocks, TPB, 0, stream>>>(aggb, w1b, b1, hb, stats1, N);

  // ---- layer 2 ----
  affine_bn<<<affBlocks, TPB, 0, stream>>>(hb, stats1, g1, be1, featb, N, invN);
  csr_agg128<<<aggBlocks, TPB, 0, stream>>>(featb, rs, csr, aggb, N);
  gemm128<<<gemmBlocks, TPB, 0, stream>>>(aggb, w2b, b2, hb, stats2, N);

  // ---- layer 3 (GEMM first, aggregate in 16-dim bf16) ----
  affine_bn<<<affBlocks, TPB, 0, stream>>>(hb, stats2, g2, be2, featb, N, invN);
  gemm_y<<<gemmBlocks, TPB, 0, stream>>>(featb, w3b, y, N);
  csr_agg10b<<<agg10Blocks, TPB, 0, stream>>>(y, rs, csr, b3, out, N);
}

// Round 11
// 586.798 us; speedup vs baseline: 1.3159x; 1.3159x over previous
//
#include <hip/hip_runtime.h>

typedef __bf16 bf16x8 __attribute__((ext_vector_type(8)));
typedef float  f32x4  __attribute__((ext_vector_type(4)));

#define LDA 136       // padded bf16 row stride for GEMM LDS tiles
#define NB_MAX 1024   // max 128-node buckets (N<=131072)

static __device__ __forceinline__ unsigned short f2bf(float f) {
  unsigned int u = __float_as_uint(f);
  u += 0x7fffu + ((u >> 16) & 1u);
  return (unsigned short)(u >> 16);
}
static __device__ __forceinline__ float bflo(unsigned int u) {
  return __uint_as_float(u << 16);
}
static __device__ __forceinline__ float bfhi(unsigned int u) {
  return __uint_as_float(u & 0xFFFF0000u);
}
static __device__ __forceinline__ unsigned int packbf2(float a, float b) {
  return (unsigned int)f2bf(a) | ((unsigned int)f2bf(b) << 16);
}

// ---------- prep: zero counters/stats + convert weights to bf16 (one dispatch)
__global__ void prep(const float* __restrict__ W1, const float* __restrict__ W2,
                     const float* __restrict__ W3, unsigned short* __restrict__ w1b,
                     unsigned short* __restrict__ w2b, unsigned short* __restrict__ w3b,
                     int* __restrict__ bcnt, float* __restrict__ s1,
                     float* __restrict__ s2, int nb) {
  int i = blockIdx.x * blockDim.x + threadIdx.x;
  if (i < nb) bcnt[i] = 0;
  if (i < 256) { s1[i] = 0.f; s2[i] = 0.f; }
  if (i < 16384) {
    w1b[i] = f2bf(W1[i]);
    w2b[i] = f2bf(W2[i]);
  } else if (i < 18432) {
    int j = i - 16384;  // 16x128 padded W3
    w3b[j] = (j < 1280) ? f2bf(W3[j]) : 0;
  }
}

// ---------- fp32 -> bf16 cast ----------
__global__ void cvt_bf16(const float* __restrict__ x,
                         unsigned short* __restrict__ o, long long n) {
  long long i = ((long long)blockIdx.x * blockDim.x + threadIdx.x) * 4;
  if (i < n) {
    float4 v = *(const float4*)(x + i);
    uint2 w;
    w.x = packbf2(v.x, v.y);
    w.y = packbf2(v.z, v.w);
    *(uint2*)(o + i) = w;
  }
}

// ---------- bucket histogram (bucket = dst >> 7); saves per-block hists ------
__global__ void bucket_hist(const int* __restrict__ ei, int* __restrict__ bcnt,
                            int* __restrict__ bhist, int E, int NB) {
  __shared__ int h[NB_MAX];
  for (int i = threadIdx.x; i < NB; i += blockDim.x) h[i] = 0;
  __syncthreads();
  int chunk = (E + gridDim.x - 1) / gridDim.x;
  int e0 = blockIdx.x * chunk;
  int e1 = min(e0 + chunk, E);
  for (int e = e0 + (int)threadIdx.x; e < e1; e += blockDim.x)
    atomicAdd(&h[ei[E + e] >> 7], 1);
  __syncthreads();
  for (int i = threadIdx.x; i < NB; i += blockDim.x) {
    bhist[blockIdx.x * NB + i] = h[i];
    if (h[i]) atomicAdd(&bcnt[i], h[i]);
  }
}

// ---------- scan bucket counts (NB<=1024, single chunk) ----------
__global__ void scan_buckets(const int* __restrict__ cnt,
                             int* __restrict__ bstart, int* __restrict__ gcur,
                             int n) {
  __shared__ int tmp[1024];
  int i = threadIdx.x;
  int v = (i < n) ? cnt[i] : 0;
  tmp[i] = v;
  __syncthreads();
  for (int off = 1; off < 1024; off <<= 1) {
    int t = (i >= off) ? tmp[i - off] : 0;
    __syncthreads();
    tmp[i] += t;
    __syncthreads();
  }
  if (i == 0) bstart[0] = 0;
  if (i < n) {
    bstart[i + 1] = tmp[i];
    gcur[i] = tmp[i] - v;  // exclusive
  }
}

// ---------- partition edges using precomputed per-block hists ----------
__global__ void partition_edges(const int* __restrict__ ei,
                                int* __restrict__ gcur,
                                const int* __restrict__ bhist,
                                unsigned int* __restrict__ part, int E, int NB) {
  __shared__ int base[NB_MAX];
  __shared__ int cur[NB_MAX];
  int chunk = (E + gridDim.x - 1) / gridDim.x;
  int e0 = blockIdx.x * chunk;
  int e1 = min(e0 + chunk, E);
  for (int i = threadIdx.x; i < NB; i += blockDim.x) {
    int hv = bhist[blockIdx.x * NB + i];
    cur[i] = 0;
    base[i] = hv ? atomicAdd(&gcur[i], hv) : 0;
  }
  __syncthreads();
  for (int e = e0 + (int)threadIdx.x; e < e1; e += blockDim.x) {
    int d = ei[E + e];
    int b = d >> 7;
    int slot = base[b] + atomicAdd(&cur[b], 1);
    part[slot] = (unsigned int)ei[e] | ((unsigned int)(d & 127) << 17);
  }
}

// ---------- counting-sort each bucket -> csr + rs ----------
__global__ void __launch_bounds__(256)
csr_fill(const unsigned int* __restrict__ part, const int* __restrict__ bstart,
         int* __restrict__ rs, int* __restrict__ csr, int N, int NB) {
  __shared__ int h[128];
  __shared__ int off[128];
  const int b = blockIdx.x;
  const int e0 = bstart[b], e1 = bstart[b + 1];
  const int tid = threadIdx.x;
  if (tid < 128) h[tid] = 0;
  __syncthreads();
  for (int i = e0 + tid; i < e1; i += 256)
    atomicAdd(&h[part[i] >> 17], 1);
  __syncthreads();
  if (tid < 128) off[tid] = h[tid];
  __syncthreads();
  for (int s = 1; s < 128; s <<= 1) {
    int v = (tid < 128 && tid >= s) ? off[tid - s] : 0;
    __syncthreads();
    if (tid < 128) off[tid] += v;
    __syncthreads();
  }
  if (tid < 128) {
    int excl = e0 + off[tid] - h[tid];
    int node = b * 128 + tid;
    if (node < N) rs[node] = excl;
    h[tid] = excl;  // reuse as cursor
  }
  if (b == NB - 1 && tid == 0) rs[N] = e1;
  __syncthreads();
  for (int i = e0 + tid; i < e1; i += 256) {
    unsigned int p = part[i];
    int slot = atomicAdd(&h[p >> 17], 1);
    csr[slot] = (int)(p & 0x1FFFF);
  }
}

// ---------- aggregation: agg[i] = t[i] + sum_j t[j], bf16, fp32 acc ----------
// one wave per node; 16 lanes x 16B cover a row; 4 edges per VMEM instruction
__global__ void __launch_bounds__(256)
csr_agg128(const unsigned short* __restrict__ t, const int* __restrict__ rs,
           const int* __restrict__ csr, unsigned short* __restrict__ agg,
           int N) {
  int node = blockIdx.x * 4 + (threadIdx.x >> 6);
  if (node >= N) return;
  const int lane = threadIdx.x & 63;
  const int q = lane >> 4;   // quarter 0..3 -> edge stride phase
  const int ql = lane & 15;  // lane within quarter
  const int c = ql * 8;      // bf16 column (16B per lane)
  float a0 = 0.f, a1 = 0.f, a2 = 0.f, a3 = 0.f;
  float a4 = 0.f, a5 = 0.f, a6 = 0.f, a7 = 0.f;
  const int b = rs[node], e = rs[node + 1];
  int i = b + q;
  for (; i + 4 < e; i += 8) {  // 2 independent 1KB gathers in flight
    int j0 = csr[i], j1 = csr[i + 4];
    uint4 v0 = *(const uint4*)(t + (long long)j0 * 128 + c);
    uint4 v1 = *(const uint4*)(t + (long long)j1 * 128 + c);
    a0 += bflo(v0.x) + bflo(v1.x);  a1 += bfhi(v0.x) + bfhi(v1.x);
    a2 += bflo(v0.y) + bflo(v1.y);  a3 += bfhi(v0.y) + bfhi(v1.y);
    a4 += bflo(v0.z) + bflo(v1.z);  a5 += bfhi(v0.z) + bfhi(v1.z);
    a6 += bflo(v0.w) + bflo(v1.w);  a7 += bfhi(v0.w) + bfhi(v1.w);
  }
  if (i < e) {
    int j = csr[i];
    uint4 v = *(const uint4*)(t + (long long)j * 128 + c);
    a0 += bflo(v.x);  a1 += bfhi(v.x);
    a2 += bflo(v.y);  a3 += bfhi(v.y);
    a4 += bflo(v.z);  a5 += bfhi(v.z);
    a6 += bflo(v.w);  a7 += bfhi(v.w);
  }
  a0 += __shfl_xor(a0, 16, 64);  a1 += __shfl_xor(a1, 16, 64);
  a2 += __shfl_xor(a2, 16, 64);  a3 += __shfl_xor(a3, 16, 64);
  a4 += __shfl_xor(a4, 16, 64);  a5 += __shfl_xor(a5, 16, 64);
  a6 += __shfl_xor(a6, 16, 64);  a7 += __shfl_xor(a7, 16, 64);
  a0 += __shfl_xor(a0, 32, 64);  a1 += __shfl_xor(a1, 32, 64);
  a2 += __shfl_xor(a2, 32, 64);  a3 += __shfl_xor(a3, 32, 64);
  a4 += __shfl_xor(a4, 32, 64);  a5 += __shfl_xor(a5, 32, 64);
  a6 += __shfl_xor(a6, 32, 64);  a7 += __shfl_xor(a7, 32, 64);
  if (q == 0) {
    uint4 sv = *(const uint4*)(t + (long long)node * 128 + c);  // self term
    uint4 w;
    w.x = packbf2(a0 + bflo(sv.x), a1 + bfhi(sv.x));
    w.y = packbf2(a2 + bflo(sv.y), a3 + bfhi(sv.y));
    w.z = packbf2(a4 + bflo(sv.z), a5 + bfhi(sv.z));
    w.w = packbf2(a6 + bflo(sv.w), a7 + bfhi(sv.w));
    *(uint4*)(agg + (long long)node * 128 + c) = w;
  }
}

// ---------- fused: agg[i] = relu(bn(h_i)) + sum_j relu(bn(h_j)) --------------
// BN coeffs derived from stats in LDS; affine applied to gathered rows inline
__global__ void __launch_bounds__(256)
csr_agg128_bn(const unsigned short* __restrict__ t, const int* __restrict__ rs,
              const int* __restrict__ csr, const float* __restrict__ stats,
              const float* __restrict__ g, const float* __restrict__ be,
              unsigned short* __restrict__ agg, int N, float invN) {
  __shared__ float lsc[128], lsh[128];
  if (threadIdx.x < 128) {
    int f = threadIdx.x;
    float mean = stats[f] * invN;
    float var = stats[128 + f] * invN - mean * mean;
    float s = g[f] * rsqrtf(var + 1e-5f);
    lsc[f] = s;
    lsh[f] = be[f] - mean * s;
  }
  __syncthreads();
  int node = blockIdx.x * 4 + (threadIdx.x >> 6);
  if (node >= N) return;
  const int lane = threadIdx.x & 63;
  const int q = lane >> 4;
  const int ql = lane & 15;
  const int c = ql * 8;
  // per-lane coefficient registers (8 features)
  float sc0 = lsc[c], sc1 = lsc[c + 1], sc2 = lsc[c + 2], sc3 = lsc[c + 3];
  float sc4 = lsc[c + 4], sc5 = lsc[c + 5], sc6 = lsc[c + 6], sc7 = lsc[c + 7];
  float sh0 = lsh[c], sh1 = lsh[c + 1], sh2 = lsh[c + 2], sh3 = lsh[c + 3];
  float sh4 = lsh[c + 4], sh5 = lsh[c + 5], sh6 = lsh[c + 6], sh7 = lsh[c + 7];
  float a0 = 0.f, a1 = 0.f, a2 = 0.f, a3 = 0.f;
  float a4 = 0.f, a5 = 0.f, a6 = 0.f, a7 = 0.f;
  const int b = rs[node], e = rs[node + 1];
  for (int i = b + q; i < e; i += 4) {
    int j = csr[i];
    uint4 v = *(const uint4*)(t + (long long)j * 128 + c);
    a0 += fmaxf(fmaf(bflo(v.x), sc0, sh0), 0.f);
    a1 += fmaxf(fmaf(bfhi(v.x), sc1, sh1), 0.f);
    a2 += fmaxf(fmaf(bflo(v.y), sc2, sh2), 0.f);
    a3 += fmaxf(fmaf(bfhi(v.y), sc3, sh3), 0.f);
    a4 += fmaxf(fmaf(bflo(v.z), sc4, sh4), 0.f);
    a5 += fmaxf(fmaf(bfhi(v.z), sc5, sh5), 0.f);
    a6 += fmaxf(fmaf(bflo(v.w), sc6, sh6), 0.f);
    a7 += fmaxf(fmaf(bfhi(v.w), sc7, sh7), 0.f);
  }
  a0 += __shfl_xor(a0, 16, 64);  a1 += __shfl_xor(a1, 16, 64);
  a2 += __shfl_xor(a2, 16, 64);  a3 += __shfl_xor(a3, 16, 64);
  a4 += __shfl_xor(a4, 16, 64);  a5 += __shfl_xor(a5, 16, 64);
  a6 += __shfl_xor(a6, 16, 64);  a7 += __shfl_xor(a7, 16, 64);
  a0 += __shfl_xor(a0, 32, 64);  a1 += __shfl_xor(a1, 32, 64);
  a2 += __shfl_xor(a2, 32, 64);  a3 += __shfl_xor(a3, 32, 64);
  a4 += __shfl_xor(a4, 32, 64);  a5 += __shfl_xor(a5, 32, 64);
  a6 += __shfl_xor(a6, 32, 64);  a7 += __shfl_xor(a7, 32, 64);
  if (q == 0) {
    uint4 sv = *(const uint4*)(t + (long long)node * 128 + c);  // self, affine
    uint4 w;
    w.x = packbf2(a0 + fmaxf(fmaf(bflo(sv.x), sc0, sh0), 0.f),
                  a1 + fmaxf(fmaf(bfhi(sv.x), sc1, sh1), 0.f));
    w.y = packbf2(a2 + fmaxf(fmaf(bflo(sv.y), sc2, sh2), 0.f),
                  a3 + fmaxf(fmaf(bfhi(sv.y), sc3, sh3), 0.f));
    w.z = packbf2(a4 + fmaxf(fmaf(bflo(sv.z), sc4, sh4), 0.f),
                  a5 + fmaxf(fmaf(bfhi(sv.z), sc5, sh5), 0.f));
    w.w = packbf2(a6 + fmaxf(fmaf(bflo(sv.w), sc6, sh6), 0.f),
                  a7 + fmaxf(fmaf(bfhi(sv.w), sc7, sh7), 0.f));
    *(uint4*)(agg + (long long)node * 128 + c) = w;
  }
}

// ---------- layer-3 aggregation on bf16 y[N,16] (8 lanes/node) ----------
__global__ void __launch_bounds__(256)
csr_agg10b(const unsigned short* __restrict__ y, const int* __restrict__ rs,
           const int* __restrict__ csr, const float* __restrict__ b3,
           float* __restrict__ out, int N) {
  int t = blockIdx.x * blockDim.x + threadIdx.x;
  int node = t >> 3;
  int c = (t & 7) * 2;
  if (node >= N) return;
  unsigned int sv = *(const unsigned int*)(y + node * 16 + c);
  float a0 = bflo(sv), a1 = bfhi(sv);
  int b = rs[node], e = rs[node + 1];
  int i = b;
  for (; i + 3 < e; i += 4) {
    int j0 = csr[i], j1 = csr[i + 1], j2 = csr[i + 2], j3 = csr[i + 3];
    unsigned int v0 = *(const unsigned int*)(y + j0 * 16 + c);
    unsigned int v1 = *(const unsigned int*)(y + j1 * 16 + c);
    unsigned int v2 = *(const unsigned int*)(y + j2 * 16 + c);
    unsigned int v3 = *(const unsigned int*)(y + j3 * 16 + c);
    a0 += bflo(v0) + bflo(v1) + bflo(v2) + bflo(v3);
    a1 += bfhi(v0) + bfhi(v1) + bfhi(v2) + bfhi(v3);
  }
  for (; i < e; ++i) {
    unsigned int v = *(const unsigned int*)(y + csr[i] * 16 + c);
    a0 += bflo(v);
    a1 += bfhi(v);
  }
  if (c < 10) {
    float2 o;
    o.x = a0 + b3[c];
    o.y = a1 + b3[c + 1];
    *(float2*)(out + node * 10 + c) = o;  // 40*node+8*(c/2): 8B aligned
  }
}

// ---------- GEMM: h_bf16 = A_bf16 @ Wb^T + bias, fused BN stats --------------
// epilogue routes C through LDS (sA reuse) for coalesced 16B stores
__global__ void __launch_bounds__(256)
gemm128(const unsigned short* __restrict__ Ab, const unsigned short* __restrict__ Wb,
        const float* __restrict__ bias, unsigned short* __restrict__ Hb,
        float* __restrict__ stats, int M) {
  __shared__ __align__(16) unsigned short sA[128 * LDA];
  __shared__ __align__(16) unsigned short sB[128 * LDA];
  __shared__ float sSum[128], sSq[128];
  const int tid = threadIdx.x;
  const int row0 = blockIdx.x * 128;

  if (tid < 128) { sSum[tid] = 0.f; sSq[tid] = 0.f; }
  for (int j = 0; j < 8; ++j) {
    int flat = j * 2048 + tid * 8;
    int r = flat >> 7, c = flat & 127;
    int gr = row0 + r;
    uint4 v = make_uint4(0, 0, 0, 0);
    if (gr < M) v = *(const uint4*)(Ab + (long long)gr * 128 + c);
    *(uint4*)(sA + r * LDA + c) = v;
  }
  for (int j = 0; j < 8; ++j) {  // W already bf16: straight copies
    int flat = j * 2048 + tid * 8;
    int r = flat >> 7, c = flat & 127;
    *(uint4*)(sB + r * LDA + c) = *(const uint4*)(Wb + flat);
  }
  __syncthreads();

  const int lane = tid & 63, wid = tid >> 6;
  const int wM = (wid >> 1) * 64, wN = (wid & 1) * 64;
  const int l15 = lane & 15, quad = lane >> 4;
  f32x4 acc[4][4] = {};

  for (int kk = 0; kk < 4; ++kk) {
    const int kb = kk * 32 + quad * 8;
    bf16x8 af[4], bfr[4];
    for (int mi = 0; mi < 4; ++mi)
      af[mi] = *reinterpret_cast<const bf16x8*>(sA + (wM + mi * 16 + l15) * LDA + kb);
    for (int ni = 0; ni < 4; ++ni)
      bfr[ni] = *reinterpret_cast<const bf16x8*>(sB + (wN + ni * 16 + l15) * LDA + kb);
    for (int mi = 0; mi < 4; ++mi)
      for (int ni = 0; ni < 4; ++ni)
        acc[mi][ni] = __builtin_amdgcn_mfma_f32_16x16x32_bf16(
            af[mi], bfr[ni], acc[mi][ni], 0, 0, 0);
  }
  __syncthreads();  // done with sA as A-tile; reuse as C staging

  for (int ni = 0; ni < 4; ++ni) {
    int col = wN + ni * 16 + l15;
    float bv = bias[col];
    float s = 0.f, q = 0.f;
    for (int mi = 0; mi < 4; ++mi) {
      int rloc = wM + mi * 16 + quad * 4;
      for (int r = 0; r < 4; ++r) {
        if (row0 + rloc + r < M) {
          float v = acc[mi][ni][r] + bv;
          sA[(rloc + r) * LDA + col] = f2bf(v);
          s += v;
          q += v * v;
        }
      }
    }
    atomicAdd(&sSum[col], s);
    atomicAdd(&sSq[col], q);
  }
  __syncthreads();
  if (tid < 128) {
    atomicAdd(&stats[tid], sSum[tid]);
    atomicAdd(&stats[128 + tid], sSq[tid]);
  }
  for (int j = 0; j < 8; ++j) {  // coalesced 16B stores
    int flat = j * 2048 + tid * 8;
    int r = flat >> 7, c = flat & 127;
    int gr = row0 + r;
    if (gr < M)
      *(uint4*)(Hb + (long long)gr * 128 + c) = *(const uint4*)(sA + r * LDA + c);
  }
}

// ---------- y = relu(bn(h)) @ w3b^T, affine fused into A-staging -------------
__global__ void __launch_bounds__(256)
gemm_y_bn(const unsigned short* __restrict__ Hb, const unsigned short* __restrict__ w3b,
          const float* __restrict__ stats, const float* __restrict__ g,
          const float* __restrict__ be, unsigned short* __restrict__ Y,
          int M, float invN) {
  __shared__ __align__(16) unsigned short sA[128 * LDA];
  __shared__ __align__(16) unsigned short sB[16 * LDA];
  __shared__ float lsc[128], lsh[128];
  const int tid = threadIdx.x;
  const int row0 = blockIdx.x * 128;

  if (tid < 128) {
    float mean = stats[tid] * invN;
    float var = stats[128 + tid] * invN - mean * mean;
    float s = g[tid] * rsqrtf(var + 1e-5f);
    lsc[tid] = s;
    lsh[tid] = be[tid] - mean * s;
  }
  __syncthreads();
  for (int j = 0; j < 8; ++j) {
    int flat = j * 2048 + tid * 8;
    int r = flat >> 7, c = flat & 127;
    int gr = row0 + r;
    uint4 v = make_uint4(0, 0, 0, 0);
    if (gr < M) v = *(const uint4*)(Hb + (long long)gr * 128 + c);
    uint4 w;
    w.x = packbf2(fmaxf(fmaf(bflo(v.x), lsc[c + 0], lsh[c + 0]), 0.f),
                  fmaxf(fmaf(bfhi(v.x), lsc[c + 1], lsh[c + 1]), 0.f));
    w.y = packbf2(fmaxf(fmaf(bflo(v.y), lsc[c + 2], lsh[c + 2]), 0.f),
                  fmaxf(fmaf(bfhi(v.y), lsc[c + 3], lsh[c + 3]), 0.f));
    w.z = packbf2(fmaxf(fmaf(bflo(v.z), lsc[c + 4], lsh[c + 4]), 0.f),
                  fmaxf(fmaf(bfhi(v.z), lsc[c + 5], lsh[c + 5]), 0.f));
    w.w = packbf2(fmaxf(fmaf(bflo(v.w), lsc[c + 6], lsh[c + 6]), 0.f),
                  fmaxf(fmaf(bfhi(v.w), lsc[c + 7], lsh[c + 7]), 0.f));
    *(uint4*)(sA + r * LDA + c) = w;
  }
  {
    int flat = tid * 8;
    int r = flat >> 7, c = flat & 127;
    *(uint4*)(sB + r * LDA + c) = *(const uint4*)(w3b + flat);
  }
  __syncthreads();

  const int lane = tid & 63, wid = tid >> 6;
  const int l15 = lane & 15, quad = lane >> 4;
  f32x4 acc[2] = {};
  for (int kk = 0; kk < 4; ++kk) {
    const int kb = kk * 32 + quad * 8;
    bf16x8 b = *reinterpret_cast<const bf16x8*>(sB + l15 * LDA + kb);
    for (int mi = 0; mi < 2; ++mi) {
      bf16x8 a = *reinterpret_cast<const bf16x8*>(
          sA + (wid * 32 + mi * 16 + l15) * LDA + kb);
      acc[mi] = __builtin_amdgcn_mfma_f32_16x16x32_bf16(a, b, acc[mi], 0, 0, 0);
    }
  }
  __syncthreads();  // reuse sA as 128x16 C staging (stride 16)
  for (int mi = 0; mi < 2; ++mi)
    for (int r = 0; r < 4; ++r) {
      int rloc = wid * 32 + mi * 16 + quad * 4 + r;
      sA[rloc * 16 + l15] = (l15 < 10) ? f2bf(acc[mi][r]) : 0;
    }
  __syncthreads();
  {
    int flat = tid * 8;
    int gr = row0 + (flat >> 4);
    if (gr < M) *(uint4*)(Y + (long long)gr * 16 + (flat & 15)) =
        *(const uint4*)(sA + flat);
  }
}

// ---------- host ----------
extern "C" void kernel_launch(void* const* d_in, const int* in_sizes, int n_in,
                              void* d_out, int out_size, void* d_ws,
                              size_t ws_size, hipStream_t stream) {
  const float* x  = (const float*)d_in[0];
  const int*   ei = (const int*)d_in[1];  // int32 per harness contract
  const float* W1 = (const float*)d_in[2];
  const float* b1 = (const float*)d_in[3];
  const float* g1 = (const float*)d_in[4];
  const float* be1 = (const float*)d_in[5];
  const float* W2 = (const float*)d_in[6];
  const float* b2 = (const float*)d_in[7];
  const float* g2 = (const float*)d_in[8];
  const float* be2 = (const float*)d_in[9];
  const float* W3 = (const float*)d_in[10];
  const float* b3 = (const float*)d_in[11];

  const int N = in_sizes[0] / 128;
  const int E = in_sizes[1] / 2;
  const int NB = (N + 127) / 128;  // 128-node buckets

  // workspace layout (~92 MB); 16B-aligned arrays first
  unsigned short* featb = (unsigned short*)d_ws;              // N*128 bf16
  unsigned short* aggb  = featb + (size_t)N * 128;            // N*128 bf16
  unsigned short* hb    = aggb + (size_t)N * 128;             // N*128 bf16
  unsigned short* w1b   = hb + (size_t)N * 128;               // 16384
  unsigned short* w2b   = w1b + 16384;                        // 16384
  unsigned short* w3b   = w2b + 16384;                        // 2048
  int*   csr = (int*)(w3b + 2048);                            // E ints
  int*   rs  = csr + E;                                       // N+1
  int* bcnt  = rs + N + 1;                                    // NB
  int* bstart = bcnt + NB;                                    // NB+1
  int* gcur  = bstart + NB + 1;                               // NB
  int* bhist = gcur + NB;                                     // 256*NB
  float* stats1 = (float*)(bhist + 256 * NB);                 // 256
  float* stats2 = stats1 + 256;                               // 256
  unsigned int* part = (unsigned int*)hb;  // aliases hb (dead until layer-1 gemm)
  unsigned short* y = featb;               // aliases featb (free in layer 3)
  float* out = (float*)d_out;

  const int TPB = 256;
  const int cvtBlocks   = (int)(((long long)N * 32 + TPB - 1) / TPB);
  const int aggBlocks   = (N + 3) / 4;
  const int agg10Blocks = (N * 8 + TPB - 1) / TPB;
  const int gemmBlocks  = (N + 127) / 128;
  const float invN = 1.0f / (float)N;

  // ---- build: weights + CSR ----
  prep<<<72, TPB, 0, stream>>>(W1, W2, W3, w1b, w2b, w3b, bcnt, stats1, stats2, NB);
  bucket_hist<<<256, TPB, 0, stream>>>(ei, bcnt, bhist, E, NB);
  scan_buckets<<<1, 1024, 0, stream>>>(bcnt, bstart, gcur, NB);
  partition_edges<<<256, TPB, 0, stream>>>(ei, gcur, bhist, part, E, NB);
  csr_fill<<<NB, TPB, 0, stream>>>(part, bstart, rs, csr, N, NB);

  // ---- layer 1 ----
  cvt_bf16<<<cvtBlocks, TPB, 0, stream>>>(x, featb, (long long)N * 128);
  csr_agg128<<<aggBlocks, TPB, 0, stream>>>(featb, rs, csr, aggb, N);
  gemm128<<<gemmBlocks, TPB, 0, stream>>>(aggb, w1b, b1, hb, stats1, N);

  // ---- layer 2 (BN1+ReLU fused into the aggregation) ----
  csr_agg128_bn<<<aggBlocks, TPB, 0, stream>>>(hb, rs, csr, stats1, g1, be1,
                                               aggb, N, invN);
  gemm128<<<gemmBlocks, TPB, 0, stream>>>(aggb, w2b, b2, hb, stats2, N);

  // ---- layer 3 (BN2+ReLU fused into gemm_y A-staging; agg in 16-dim) ----
  gemm_y_bn<<<gemmBlocks, TPB, 0, stream>>>(hb, w3b, stats2, g2, be2, y, N, invN);
  csr_agg10b<<<agg10Blocks, TPB, 0, stream>>>(y, rs, csr, b3, out, N);
}